// Round 3
// baseline (432.439 us; speedup 1.0000x reference)
//
#include <hip/hip_runtime.h>

// GCN ensemble: atomic-free counting-sort CSR (256-node buckets) + FUSED
// (gather_l1 + MLP) kernel + gather_l2.
// R11: evidence says the gather wall is L2-MISS traffic (FETCH 170MB @ 2.0TB/s
// ~= per-XCD L2-fill rate), not wave parallelism. Two levers:
//  (a) XCD-branch partitioning in k_gather_mlp: dispatch is round-robin
//      bid%8 -> XCD, so groups of 4 consecutive blocks pin branch a to XCDs
//      0-3 and branch b to 4-7 -> per-XCD working set 25.6 -> 12.8 MB.
//  (b) wave_stream: 16-deep load batches + dual float2 accumulators
//      (v_pk_add_f32), halving the dependent add chain and doubling
//      outstanding misses per wave.
// Math unchanged: agg[d] = dinv_d * (sum_s g[s] + g[d]), g = dinv*h (bf16).

typedef unsigned int uint;
typedef unsigned short ushort;
typedef __attribute__((ext_vector_type(8))) short bf8_t;
typedef __attribute__((ext_vector_type(4))) float f4_t;

#define CHUNK 4096   // edges per WG in P1/P3; NW = ceil(e/CHUNK) <= 256
#define BKT 256      // nodes per bucket; NB = ceil(n/256) <= 256, needs n < 2^17

__device__ inline ushort f2bf(float f) {
    uint u = __float_as_uint(f);
    return (ushort)((u + 0x7fff + ((u >> 16) & 1)) >> 16);
}
__device__ inline float bf2f(ushort h) { return __uint_as_float(((uint)h) << 16); }

// ---------- P1: per-chunk bucket histogram (LDS), dense writes ----------
__global__ __launch_bounds__(256) void k_p1_hist(
    const int* __restrict__ ei_a, const int* __restrict__ ei_b,
    int* __restrict__ cnt_mat, int e, int NB, int NW) {
    __shared__ int lh[BKT];
    int l = blockIdx.x / NW, w = blockIdx.x % NW;
    const int* dst = (l ? ei_b : ei_a) + e;
    if (threadIdx.x < NB) lh[threadIdx.x] = 0;
    __syncthreads();
    int beg = w * CHUNK, end = min(beg + CHUNK, e);
    for (int j = beg + threadIdx.x; j < end; j += 256) atomicAdd(&lh[dst[j] >> 8], 1);
    __syncthreads();
    int* outp = cnt_mat + ((size_t)l * NW + w) * NB;
    if (threadIdx.x < NB) outp[threadIdx.x] = lh[threadIdx.x];
}

// ---------- P2a: per-bucket exclusive prefix over WGs (one block per bucket) ----------
__global__ __launch_bounds__(256) void k_p2a(const int* __restrict__ cnt_mat,
                                             int* __restrict__ wgoff, int* __restrict__ btot,
                                             int NB, int NW) {
    __shared__ int s[256];
    int which = blockIdx.x;  // 0..2*NB-1
    int l = which / NB, b = which - l * NB;
    int t = threadIdx.x;
    int v = (t < NW) ? cnt_mat[((size_t)l * NW + t) * NB + b] : 0;
    s[t] = v;
    __syncthreads();
    for (int o = 1; o < 256; o <<= 1) {
        int x = 0;
        if (t >= o) x = s[t - o];
        __syncthreads();
        s[t] += x;
        __syncthreads();
    }
    if (t < NW) wgoff[((size_t)l * NB + b) * NW + t] = s[t] - v;
    if (t == 255) btot[which] = s[255];
}

// ---------- P2b: exclusive scan of bucket totals per list (one WG, NB<=256) ----------
__global__ __launch_bounds__(256) void k_p2b(const int* __restrict__ btot,
                                             int* __restrict__ boff, int NB, int e) {
    __shared__ int s[256];
    for (int l = 0; l < 2; ++l) {
        int t = threadIdx.x;
        int v = (t < NB) ? btot[l * NB + t] : 0;
        s[t] = v;
        __syncthreads();
        for (int o = 1; o < 256; o <<= 1) {
            int x = 0;
            if (t >= o) x = s[t - o];
            __syncthreads();
            s[t] += x;
            __syncthreads();
        }
        if (t < NB) boff[l * (NB + 1) + t] = s[t] - v;
        if (t == 0) boff[l * (NB + 1) + NB] = e;
        __syncthreads();
    }
}

// ---------- P3: scatter packed entries into contiguous per-(WG,bucket) segments ----------
__global__ __launch_bounds__(256) void k_p3_scatter(
    const int* __restrict__ ei_a, const int* __restrict__ ei_b,
    const int* __restrict__ wgoff, const int* __restrict__ boff,
    int* __restrict__ ebuf_a, int* __restrict__ ebuf_b, int e, int NB, int NW) {
    __shared__ int base[BKT];
    __shared__ int bump[BKT];
    int l = blockIdx.x / NW, w = blockIdx.x % NW;
    const int* ei = l ? ei_b : ei_a;
    int* ebuf = l ? ebuf_b : ebuf_a;
    if (threadIdx.x < NB) {
        base[threadIdx.x] = boff[l * (NB + 1) + threadIdx.x] +
                            wgoff[((size_t)l * NB + threadIdx.x) * NW + w];
        bump[threadIdx.x] = 0;
    }
    __syncthreads();
    int beg = w * CHUNK, end = min(beg + CHUNK, e);
    for (int j = beg + threadIdx.x; j < end; j += 256) {
        int sv = ei[j], d = ei[e + j];
        int b = d >> 8;
        int pos = base[b] + atomicAdd(&bump[b], 1);
        ebuf[pos] = ((d & 255) << 17) | sv;  // needs src < 2^17
    }
}

// ---------- P4: within-bucket node sort -> final CSR + noff + dinv ----------
__global__ __launch_bounds__(256) void k_p4_nodesort(
    const int* __restrict__ ebuf_a, const int* __restrict__ ebuf_b,
    const int* __restrict__ boff, int* __restrict__ csr_a, int* __restrict__ csr_b,
    int* __restrict__ noff, float* __restrict__ dinv, int n, int e, int NB) {
    __shared__ int hist[256], nstart[256], sc[256];
    int which = blockIdx.x;
    int l = which / NB, b = which - l * NB;
    const int* ebuf = l ? ebuf_b : ebuf_a;
    int* csr = l ? csr_b : csr_a;
    int seg0 = boff[l * (NB + 1) + b], seg1 = boff[l * (NB + 1) + b + 1];
    int t = threadIdx.x;
    hist[t] = 0;
    __syncthreads();
    for (int j = seg0 + t; j < seg1; j += 256) atomicAdd(&hist[ebuf[j] >> 17], 1);
    __syncthreads();
    int v = hist[t];
    sc[t] = v;
    __syncthreads();
    for (int o = 1; o < 256; o <<= 1) {
        int x = 0;
        if (t >= o) x = sc[t - o];
        __syncthreads();
        sc[t] += x;
        __syncthreads();
    }
    nstart[t] = seg0 + sc[t] - v;
    int node = b * BKT + t;
    if (node < n) {
        noff[(size_t)l * (n + 1) + node] = nstart[t];
        dinv[(size_t)l * n + node] = rsqrtf((float)v + 1.0f);
    }
    hist[t] = 0;  // reuse as bump counter
    if (b == NB - 1 && t == 0) noff[(size_t)l * (n + 1) + n] = e;
    __syncthreads();
    for (int j = seg0 + t; j < seg1; j += 256) {
        int pk = ebuf[j];
        int ni = pk >> 17;
        int pos = nstart[ni] + atomicAdd(&hist[ni], 1);
        csr[pos] = pk;  // keep dst&255 in bits 17..24 for the row-owned stream
    }
}

// ---------- fused cvt (x -> per-branch dinv-scaled bf16) + weight packing ----------
__global__ void k_cvt_pack(const float2* __restrict__ x2, const float* __restrict__ dinv,
                           uint* __restrict__ xba, uint* __restrict__ xbb,
                           const float* __restrict__ W0, const float* __restrict__ W1,
                           const float* __restrict__ W2, const float* __restrict__ W3,
                           ushort* __restrict__ Wpb, int n, int cvtb) {
    if ((int)blockIdx.x < cvtb) {
        int i = blockIdx.x * 256 + threadIdx.x;
        if (i >= n * 64) return;
        int node = i >> 6;
        float da = dinv[node], db = dinv[n + node];
        float2 v = x2[i];
        xba[i] = (uint)f2bf(da * v.x) | ((uint)f2bf(da * v.y) << 16);
        xbb[i] = (uint)f2bf(db * v.x) | ((uint)f2bf(db * v.y) << 16);
    } else {
        int i = (blockIdx.x - cvtb) * 256 + threadIdx.x;
        if (i >= 4 * 32768) return;
        int seg = i >> 15;
        int r = i & 32767;
        const float* W = seg == 0 ? W0 : seg == 1 ? W1 : seg == 2 ? W2 : W3;
        int N = seg < 2 ? 256 : 128;
        int k = r / N, nn = r - k * N;
        int kt = k >> 5, q = (k & 31) >> 3, jj = k & 7;
        int nt = nn >> 4, ln = q * 16 + (nn & 15);
        int NT = N >> 4;
        Wpb[(size_t)seg * 32768 + (((size_t)(kt * NT + nt)) * 64 + ln) * 8 + jj] = f2bf(W[r]);
    }
}

// ---------- row-owned edge stream (NO atomics), 16-deep, dual accumulators ----------
// Wave owns nodes [a0, a1) (<= 8 consecutive, within one 32-row block at
// rowbase). Streams its contiguous dst-sorted CSR range in 16-deep load
// batches crossing node boundaries; dual register accumulator pairs (halved
// dependent-add chain, pk_add); plain ds_write flush on row change. Each
// owned row is flushed exactly once -> no zero-init, no races. Edge words
// readfirstlane'd -> scalar row logic, SGPR-base + lane loads.
__device__ inline void wave_stream(const uint* __restrict__ xb, const int* __restrict__ csr,
                                   int ebeg, int eend, int a0, int a1, int lane, int rowbase,
                                   float* __restrict__ accLo, float* __restrict__ accHi) {
    int bkt0 = rowbase & ~255;  // bucket base (blocks never span buckets)
    int cur = a0;
    float sx0 = 0.f, sy0 = 0.f, sx1 = 0.f, sy1 = 0.f;
    int j = ebeg;
    for (; j + 16 <= eend; j += 16) {
        int ew[16];
        {
            int4 ea = *(const int4*)(csr + j);
            int4 eb = *(const int4*)(csr + j + 4);
            int4 ec = *(const int4*)(csr + j + 8);
            int4 ed = *(const int4*)(csr + j + 12);
            ew[0] = __builtin_amdgcn_readfirstlane(ea.x);
            ew[1] = __builtin_amdgcn_readfirstlane(ea.y);
            ew[2] = __builtin_amdgcn_readfirstlane(ea.z);
            ew[3] = __builtin_amdgcn_readfirstlane(ea.w);
            ew[4] = __builtin_amdgcn_readfirstlane(eb.x);
            ew[5] = __builtin_amdgcn_readfirstlane(eb.y);
            ew[6] = __builtin_amdgcn_readfirstlane(eb.z);
            ew[7] = __builtin_amdgcn_readfirstlane(eb.w);
            ew[8] = __builtin_amdgcn_readfirstlane(ec.x);
            ew[9] = __builtin_amdgcn_readfirstlane(ec.y);
            ew[10] = __builtin_amdgcn_readfirstlane(ec.z);
            ew[11] = __builtin_amdgcn_readfirstlane(ec.w);
            ew[12] = __builtin_amdgcn_readfirstlane(ed.x);
            ew[13] = __builtin_amdgcn_readfirstlane(ed.y);
            ew[14] = __builtin_amdgcn_readfirstlane(ed.z);
            ew[15] = __builtin_amdgcn_readfirstlane(ed.w);
        }
        uint u[16];
#pragma unroll
        for (int k = 0; k < 16; ++k)
            u[k] = xb[(uint)(ew[k] & 0x1ffff) * 64u + lane];
#pragma unroll
        for (int k = 0; k < 16; ++k) {
            int rr = bkt0 | ((ew[k] >> 17) & 255);
            if (rr != cur) {
                accLo[(cur - rowbase) * 64 + lane] = sx0 + sx1;
                accHi[(cur - rowbase) * 64 + lane] = sy0 + sy1;
                for (int c = cur + 1; c < rr; ++c) {
                    accLo[(c - rowbase) * 64 + lane] = 0.f;
                    accHi[(c - rowbase) * 64 + lane] = 0.f;
                }
                cur = rr;
                sx0 = sy0 = sx1 = sy1 = 0.f;
            }
            float lx = __uint_as_float(u[k] << 16);
            float ly = __uint_as_float(u[k] & 0xffff0000u);
            if (k & 1) { sx1 += lx; sy1 += ly; } else { sx0 += lx; sy0 += ly; }
        }
    }
    if (j < eend) {
        int last = eend - 1;
        int ew[16];
        uint u[16];
#pragma unroll
        for (int k = 0; k < 16; ++k) {
            int jj = j + k;
            jj = jj > last ? last : jj;
            ew[k] = __builtin_amdgcn_readfirstlane(csr[jj]);
        }
#pragma unroll
        for (int k = 0; k < 16; ++k)
            u[k] = xb[(uint)(ew[k] & 0x1ffff) * 64u + lane];
#pragma unroll
        for (int k = 0; k < 16; ++k) {
            if (j + k > last) break;  // wave-uniform
            int rr = bkt0 | ((ew[k] >> 17) & 255);
            if (rr != cur) {
                accLo[(cur - rowbase) * 64 + lane] = sx0 + sx1;
                accHi[(cur - rowbase) * 64 + lane] = sy0 + sy1;
                for (int c = cur + 1; c < rr; ++c) {
                    accLo[(c - rowbase) * 64 + lane] = 0.f;
                    accHi[(c - rowbase) * 64 + lane] = 0.f;
                }
                cur = rr;
                sx0 = sy0 = sx1 = sy1 = 0.f;
            }
            float lx = __uint_as_float(u[k] << 16);
            float ly = __uint_as_float(u[k] & 0xffff0000u);
            if (k & 1) { sx1 += lx; sy1 += ly; } else { sx0 += lx; sy0 += ly; }
        }
    }
    // final flush: cur gets the running sums; remaining owned rows get zeros
    accLo[(cur - rowbase) * 64 + lane] = sx0 + sx1;
    accHi[(cur - rowbase) * 64 + lane] = sy0 + sy1;
    for (int c = cur + 1; c < a1; ++c) {
        accLo[(c - rowbase) * 64 + lane] = 0.f;
        accHi[(c - rowbase) * 64 + lane] = 0.f;
    }
}

// ---------- FUSED gather_l1 + MLP ----------
// Block = 32 nodes, 4 waves (8 owned nodes each). XCD-branch partitioning:
// dispatch round-robins bid%8 -> XCD, so group-of-4 parity pins branch a to
// XCDs 0-3 and branch b to XCDs 4-7 (per-XCD table working set 25.6->12.8MB).
// Phase 1: row-owned stream into f32 LDS acc tiles. Finalize:
// A = f2bf(dinv*(acc+self)) with the 16B-block rotation swizzle. Phase 2: MLP.
// LDS aliasing: acc(16K)+hs(16.9K) share [0,16896); A-tile at [16896,25088).
// Total 25088 B -> 6 blocks/CU.
__global__ __launch_bounds__(256) void k_gather_mlp(
    const uint* __restrict__ xba, const uint* __restrict__ xbb,
    const int* __restrict__ csr_a, const int* __restrict__ csr_b,
    const int* __restrict__ noff, const float* __restrict__ dinv,
    const ushort* __restrict__ Wpb, const float* __restrict__ b0,
    const float* __restrict__ b1, ushort* __restrict__ oa, ushort* __restrict__ ob,
    int n, int nblk) {
    constexpr int HW = 264;            // h-tile row stride (ushorts)
    __shared__ uint lds[6272];         // 25088 B
    float* accLo = (float*)lds;        // [32][64] f32, even feats
    float* accHi = (float*)(lds + 2048);  // [32][64] f32, odd feats
    uint* As32 = lds + 4224;           // [32][64] bf16x2 (rotated 16B blocks), 8KB
    ushort* hs = (ushort*)lds;         // [32][264] bf16, aliases acc (acc dead by then)

    // XCD-branch partition: groups of 4 consecutive blocks -> XCDs {0-3} / {4-7}
    int g = blockIdx.x >> 2;
    int br = g & 1;
    int blk = (g >> 1) * 4 + (blockIdx.x & 3);
    if (blk >= nblk) return;  // uniform over the block, before any barrier

    const uint* xb = br ? xbb : xba;
    const int* csr = br ? csr_b : csr_a;
    const int* no = noff + (size_t)br * (n + 1);
    const float* dv = dinv + (size_t)br * n;
    const ushort* W1 = Wpb + (br ? 32768 : 0);
    const ushort* W2 = Wpb + (br ? 3 * 32768 : 2 * 32768);
    const float* bias = br ? b1 : b0;
    ushort* Cout = br ? ob : oa;

    const int t = threadIdx.x;
    const int lane = t & 63;
    const int wave = t >> 6;
    const int l15 = lane & 15;
    const int quad = lane >> 4;
    const int row0 = blk * 32;

    // ---- phase 1: row-owned stream (8 nodes per wave) ----
    {
        int a0 = row0 + wave * 8;
        if (a0 < n) {
            int a1 = min(a0 + 8, n);
            int ebeg = __builtin_amdgcn_readfirstlane(no[a0]);
            int eend = __builtin_amdgcn_readfirstlane(no[a1]);
            wave_stream(xb, csr, ebeg, eend, a0, a1, lane, row0, accLo, accHi);
        }
    }
    __syncthreads();

    // ---- finalize: A[r][f] = f2bf(dinv*(acc + self)), rotated 16B blocks ----
    {
        int r = t >> 3, cb = t & 7;   // row, 16-feat column block
        int node = row0 + r;
        float di = 0.f;
        uint4 s0 = (uint4){0, 0, 0, 0}, s1 = (uint4){0, 0, 0, 0};
        if (node < n) {
            di = dv[node];
            const uint4* xp = (const uint4*)(xb + (size_t)node * 64 + cb * 8);
            s0 = xp[0];
            s1 = xp[1];
        }
        const float* aL = accLo + r * 64 + cb * 8;
        const float* aH = accHi + r * 64 + cb * 8;
        uint us[8];
        us[0] = s0.x; us[1] = s0.y; us[2] = s0.z; us[3] = s0.w;
        us[4] = s1.x; us[5] = s1.y; us[6] = s1.z; us[7] = s1.w;
        uint dw[8];
#pragma unroll
        for (int k = 0; k < 8; ++k) {
            float lo = (node < n) ? di * (aL[k] + bf2f((ushort)us[k])) : 0.f;
            float hi = (node < n) ? di * (aH[k] + bf2f((ushort)(us[k] >> 16))) : 0.f;
            dw[k] = (uint)f2bf(lo) | ((uint)f2bf(hi) << 16);
        }
        int b0i = cb * 2;
        *(uint4*)&As32[r * 64 + ((b0i + r) & 15) * 4] = (uint4){dw[0], dw[1], dw[2], dw[3]};
        *(uint4*)&As32[r * 64 + ((b0i + 1 + r) & 15) * 4] = (uint4){dw[4], dw[5], dw[6], dw[7]};
    }
    __syncthreads();

    // ---- phase 2a: h[32x64 cols @ wave*64] = relu(A@W1 + b) ----
    {
        f4_t acc[2][4];
#pragma unroll
        for (int a = 0; a < 2; ++a)
#pragma unroll
            for (int b = 0; b < 4; ++b) acc[a][b] = (f4_t){0.f, 0.f, 0.f, 0.f};

#pragma unroll
        for (int kt = 0; kt < 4; ++kt) {
            bf8_t af[2];
#pragma unroll
            for (int mi = 0; mi < 2; ++mi) {
                int rr = mi * 16 + l15;
                int blk16 = (kt * 4 + quad + rr) & 15;  // un-rotate
                af[mi] = *(const bf8_t*)&As32[rr * 64 + blk16 * 4];
            }
#pragma unroll
            for (int nj = 0; nj < 4; ++nj) {
                int nt = wave * 4 + nj;
                bf8_t wf = *(const bf8_t*)(W1 + (((size_t)(kt * 16 + nt)) * 64 + lane) * 8);
#pragma unroll
                for (int mi = 0; mi < 2; ++mi)
                    acc[mi][nj] = __builtin_amdgcn_mfma_f32_16x16x32_bf16(af[mi], wf, acc[mi][nj], 0, 0, 0);
            }
        }
#pragma unroll
        for (int nj = 0; nj < 4; ++nj) {
            int col = wave * 64 + nj * 16 + l15;
            float bv = bias[col];
#pragma unroll
            for (int mi = 0; mi < 2; ++mi)
#pragma unroll
                for (int r = 0; r < 4; ++r)
                    hs[(mi * 16 + quad * 4 + r) * HW + col] = f2bf(fmaxf(acc[mi][nj][r] + bv, 0.f));
        }
    }
    __syncthreads();

    // ---- phase 2b: C[32x32 cols @ wave*32] = (h@W2)*dinv ----
    {
        f4_t acc2[2][2];
#pragma unroll
        for (int a = 0; a < 2; ++a)
#pragma unroll
            for (int b = 0; b < 2; ++b) acc2[a][b] = (f4_t){0.f, 0.f, 0.f, 0.f};

#pragma unroll
        for (int kt = 0; kt < 8; ++kt) {
            bf8_t af[2];
#pragma unroll
            for (int mi = 0; mi < 2; ++mi)
                af[mi] = *(const bf8_t*)&hs[(mi * 16 + l15) * HW + kt * 32 + quad * 8];
#pragma unroll
            for (int nj = 0; nj < 2; ++nj) {
                int nt = wave * 2 + nj;
                bf8_t wf = *(const bf8_t*)(W2 + (((size_t)(kt * 8 + nt)) * 64 + lane) * 8);
#pragma unroll
                for (int mi = 0; mi < 2; ++mi)
                    acc2[mi][nj] = __builtin_amdgcn_mfma_f32_16x16x32_bf16(af[mi], wf, acc2[mi][nj], 0, 0, 0);
            }
        }
#pragma unroll
        for (int nj = 0; nj < 2; ++nj) {
            int col = wave * 32 + nj * 16 + l15;
#pragma unroll
            for (int mi = 0; mi < 2; ++mi)
#pragma unroll
                for (int r = 0; r < 4; ++r) {
                    int row = row0 + mi * 16 + quad * 4 + r;
                    if (row < n)
                        Cout[(size_t)row * 128 + col] = f2bf(acc2[mi][nj][r] * dv[row]);
                }
        }
    }
}

// ---------- gather_l2: 32-node blocks, both branches via row-owned streams ----------
// LDS = 4 x [32][64] f32 = 32 KB -> 5 blocks/CU. All blocks stream table A
// then table B (phase-aligned -> ~12.8MB working set already). Finalize fuses
// self terms, dinv scaling, bias (b2+b3) and the float32 output store.
__global__ __launch_bounds__(256) void k_gather_l2(
    const uint* __restrict__ hba, const uint* __restrict__ hbb,
    const int* __restrict__ csr_a, const int* __restrict__ csr_b,
    const int* __restrict__ noff, const float* __restrict__ dinv,
    const float* __restrict__ b2, const float* __restrict__ b3,
    float* __restrict__ out, int n) {
    __shared__ uint lds[8192];  // 32 KB
    float* aLoA = (float*)lds;
    float* aHiA = (float*)(lds + 2048);
    float* aLoB = (float*)(lds + 4096);
    float* aHiB = (float*)(lds + 6144);

    const int t = threadIdx.x;
    const int lane = t & 63;
    const int wave = t >> 6;
    const int row0 = blockIdx.x * 32;

    {
        int a0 = row0 + wave * 8;
        if (a0 < n) {
            int a1 = min(a0 + 8, n);
            int ebeg = __builtin_amdgcn_readfirstlane(noff[a0]);
            int eend = __builtin_amdgcn_readfirstlane(noff[a1]);
            wave_stream(hba, csr_a, ebeg, eend, a0, a1, lane, row0, aLoA, aHiA);
            const int* no_b = noff + (n + 1);
            int ebeg2 = __builtin_amdgcn_readfirstlane(no_b[a0]);
            int eend2 = __builtin_amdgcn_readfirstlane(no_b[a1]);
            wave_stream(hbb, csr_b, ebeg2, eend2, a0, a1, lane, row0, aLoB, aHiB);
        }
    }
    __syncthreads();

    int r = t >> 3, cb = t & 7;
    int node = row0 + r;
    if (node >= n) return;
    float fa = dinv[node], fb = dinv[n + node];
    const uint4* xa = (const uint4*)(hba + (size_t)node * 64 + cb * 8);
    const uint4* xbp = (const uint4*)(hbb + (size_t)node * 64 + cb * 8);
    uint4 a0v = xa[0], a1v = xa[1];
    uint4 c0 = xbp[0], c1 = xbp[1];
    uint ua[8], ub[8];
    ua[0] = a0v.x; ua[1] = a0v.y; ua[2] = a0v.z; ua[3] = a0v.w;
    ua[4] = a1v.x; ua[5] = a1v.y; ua[6] = a1v.z; ua[7] = a1v.w;
    ub[0] = c0.x; ub[1] = c0.y; ub[2] = c0.z; ub[3] = c0.w;
    ub[4] = c1.x; ub[5] = c1.y; ub[6] = c1.z; ub[7] = c1.w;

    const float4* b2v = (const float4*)(b2 + cb * 16);
    const float4* b3v = (const float4*)(b3 + cb * 16);
    const float* aLA = aLoA + r * 64 + cb * 8;
    const float* aHA = aHiA + r * 64 + cb * 8;
    const float* aLB = aLoB + r * 64 + cb * 8;
    const float* aHB = aHiB + r * 64 + cb * 8;

    float res[16];
#pragma unroll
    for (int k = 0; k < 8; ++k) {
        res[2 * k] = fa * (aLA[k] + bf2f((ushort)ua[k])) +
                     fb * (aLB[k] + bf2f((ushort)ub[k]));
        res[2 * k + 1] = fa * (aHA[k] + bf2f((ushort)(ua[k] >> 16))) +
                         fb * (aHB[k] + bf2f((ushort)(ub[k] >> 16)));
    }
    float4* op = (float4*)(out + (size_t)node * 128 + cb * 16);
#pragma unroll
    for (int i = 0; i < 4; ++i) {
        float4 bsum2 = b2v[i];
        float4 bsum3 = b3v[i];
        float4 o;
        o.x = res[4 * i + 0] + bsum2.x + bsum3.x;
        o.y = res[4 * i + 1] + bsum2.y + bsum3.y;
        o.z = res[4 * i + 2] + bsum2.z + bsum3.z;
        o.w = res[4 * i + 3] + bsum2.w + bsum3.w;
        op[i] = o;
    }
}

extern "C" void kernel_launch(void* const* d_in, const int* in_sizes, int n_in,
                              void* d_out, int out_size, void* d_ws, size_t ws_size,
                              hipStream_t stream) {
    const float* x    = (const float*)d_in[0];
    const int*   ei_a = (const int*)d_in[1];
    const int*   ei_b = (const int*)d_in[2];
    const float* W0 = (const float*)d_in[3];
    const float* b0 = (const float*)d_in[4];
    const float* W1 = (const float*)d_in[5];
    const float* b1 = (const float*)d_in[6];
    const float* W2 = (const float*)d_in[7];
    const float* b2 = (const float*)d_in[8];
    const float* W3 = (const float*)d_in[9];
    const float* b3 = (const float*)d_in[10];
    float* out = (float*)d_out;

    const int n = in_sizes[0] / 128;  // 50000 (< 2^17)
    const int e = in_sizes[1] / 2;    // 800000
    const int NB = (n + BKT - 1) / BKT;      // 196 (<= 256)
    const int NW = (e + CHUNK - 1) / CHUNK;  // 196 (<= 256)

    // workspace (~92 MB)
    float*  ws   = (float*)d_ws;
    float*  dinv = ws;                                // 2n
    uint*   xba  = (uint*)(ws + 2 * (size_t)n);       // 64n
    uint*   xbb  = xba + 64 * (size_t)n;              // 64n
    uint*   oa   = xbb + 64 * (size_t)n;              // 64n (bf16 g, branch a)
    uint*   ob   = oa + 64 * (size_t)n;               // 64n
    ushort* Wpb  = (ushort*)(ob + 64 * (size_t)n);    // 4*32768 ushort
    int* cnt_mat = (int*)(Wpb + 4 * 32768);           // 2*NW*NB
    int* wgoff   = cnt_mat + 2 * (size_t)NW * NB;     // 2*NB*NW
    int* btot    = wgoff + 2 * (size_t)NB * NW;       // 2*NB
    int* boff    = btot + 2 * NB;                     // 2*(NB+1)
    int* noff    = boff + 2 * (NB + 1);               // 2*(n+1)
    int* ebuf_a  = noff + 2 * (n + 1);                // e
    int* ebuf_b  = ebuf_a + e;                        // e
    int* csr_a   = ebuf_b + e;                        // e
    int* csr_b   = csr_a + e;                         // e

    const int B = 256;

    // --- CSR build (atomic-free) ---
    k_p1_hist<<<2 * NW, B, 0, stream>>>(ei_a, ei_b, cnt_mat, e, NB, NW);
    k_p2a<<<2 * NB, B, 0, stream>>>(cnt_mat, wgoff, btot, NB, NW);
    k_p2b<<<1, B, 0, stream>>>(btot, boff, NB, e);
    k_p3_scatter<<<2 * NW, B, 0, stream>>>(ei_a, ei_b, wgoff, boff, ebuf_a, ebuf_b, e, NB, NW);
    k_p4_nodesort<<<2 * NB, B, 0, stream>>>(ebuf_a, ebuf_b, boff, csr_a, csr_b, noff, dinv,
                                            n, e, NB);

    // --- conversions (fused cvt + weight pack) ---
    const int cvtb = (n * 64 + B - 1) / B;
    const int packb = (4 * 32768 + B - 1) / B;
    k_cvt_pack<<<cvtb + packb, B, 0, stream>>>((const float2*)x, dinv, xba, xbb,
                                               W0, W1, W2, W3, Wpb, n, cvtb);

    // --- fused layer-1 gather + MLP, both branches, XCD-branch partitioned ---
    const int nblk = (n + 31) / 32;
    const int grp4 = (nblk + 3) / 4;   // groups of 4 blocks; 2 branches alternate
    k_gather_mlp<<<grp4 * 8, B, 0, stream>>>(xba, xbb, csr_a, csr_b, noff, dinv, Wpb,
                                             b0, b1, (ushort*)oa, (ushort*)ob, n, nblk);

    // --- layer-2 aggregation + ensemble sum + bias (row-owned stream blocks) ---
    k_gather_l2<<<nblk, B, 0, stream>>>(oa, ob, csr_a, csr_b, noff, dinv, b2, b3, out, n);
}

// Round 4
// 289.872 us; speedup vs baseline: 1.4918x; 1.4918x over previous
//
#include <hip/hip_runtime.h>

// GCN ensemble: atomic-free counting-sort CSR (256-node buckets) + FUSED
// (gather_l1 + MLP) kernel + gather_l2.
// R12: R11's 16-deep batching spilled to scratch (WRITE_SIZE 26->119MB = ~93MB
// scratch; VGPR 44->68; VALUBusy down) and regressed 2x. Revert wave_stream to
// the proven R10 8-deep form (VGPR 44, no spill). KEEP ONLY the XCD-branch
// partitioning in k_gather_mlp as a clean single-lever A/B vs R10:
//   dispatch round-robins bid%8 -> XCD, so group-of-4 parity pins branch a to
//   XCDs 0-3 and branch b to 4-7 (per-XCD gather table 25.6 -> 12.8 MB).
// Math unchanged: agg[d] = dinv_d * (sum_s g[s] + g[d]), g = dinv*h (bf16).

typedef unsigned int uint;
typedef unsigned short ushort;
typedef __attribute__((ext_vector_type(8))) short bf8_t;
typedef __attribute__((ext_vector_type(4))) float f4_t;

#define CHUNK 4096   // edges per WG in P1/P3; NW = ceil(e/CHUNK) <= 256
#define BKT 256      // nodes per bucket; NB = ceil(n/256) <= 256, needs n < 2^17

__device__ inline ushort f2bf(float f) {
    uint u = __float_as_uint(f);
    return (ushort)((u + 0x7fff + ((u >> 16) & 1)) >> 16);
}
__device__ inline float bf2f(ushort h) { return __uint_as_float(((uint)h) << 16); }

// ---------- P1: per-chunk bucket histogram (LDS), dense writes ----------
__global__ __launch_bounds__(256) void k_p1_hist(
    const int* __restrict__ ei_a, const int* __restrict__ ei_b,
    int* __restrict__ cnt_mat, int e, int NB, int NW) {
    __shared__ int lh[BKT];
    int l = blockIdx.x / NW, w = blockIdx.x % NW;
    const int* dst = (l ? ei_b : ei_a) + e;
    if (threadIdx.x < NB) lh[threadIdx.x] = 0;
    __syncthreads();
    int beg = w * CHUNK, end = min(beg + CHUNK, e);
    for (int j = beg + threadIdx.x; j < end; j += 256) atomicAdd(&lh[dst[j] >> 8], 1);
    __syncthreads();
    int* outp = cnt_mat + ((size_t)l * NW + w) * NB;
    if (threadIdx.x < NB) outp[threadIdx.x] = lh[threadIdx.x];
}

// ---------- P2a: per-bucket exclusive prefix over WGs (one block per bucket) ----------
__global__ __launch_bounds__(256) void k_p2a(const int* __restrict__ cnt_mat,
                                             int* __restrict__ wgoff, int* __restrict__ btot,
                                             int NB, int NW) {
    __shared__ int s[256];
    int which = blockIdx.x;  // 0..2*NB-1
    int l = which / NB, b = which - l * NB;
    int t = threadIdx.x;
    int v = (t < NW) ? cnt_mat[((size_t)l * NW + t) * NB + b] : 0;
    s[t] = v;
    __syncthreads();
    for (int o = 1; o < 256; o <<= 1) {
        int x = 0;
        if (t >= o) x = s[t - o];
        __syncthreads();
        s[t] += x;
        __syncthreads();
    }
    if (t < NW) wgoff[((size_t)l * NB + b) * NW + t] = s[t] - v;
    if (t == 255) btot[which] = s[255];
}

// ---------- P2b: exclusive scan of bucket totals per list (one WG, NB<=256) ----------
__global__ __launch_bounds__(256) void k_p2b(const int* __restrict__ btot,
                                             int* __restrict__ boff, int NB, int e) {
    __shared__ int s[256];
    for (int l = 0; l < 2; ++l) {
        int t = threadIdx.x;
        int v = (t < NB) ? btot[l * NB + t] : 0;
        s[t] = v;
        __syncthreads();
        for (int o = 1; o < 256; o <<= 1) {
            int x = 0;
            if (t >= o) x = s[t - o];
            __syncthreads();
            s[t] += x;
            __syncthreads();
        }
        if (t < NB) boff[l * (NB + 1) + t] = s[t] - v;
        if (t == 0) boff[l * (NB + 1) + NB] = e;
        __syncthreads();
    }
}

// ---------- P3: scatter packed entries into contiguous per-(WG,bucket) segments ----------
__global__ __launch_bounds__(256) void k_p3_scatter(
    const int* __restrict__ ei_a, const int* __restrict__ ei_b,
    const int* __restrict__ wgoff, const int* __restrict__ boff,
    int* __restrict__ ebuf_a, int* __restrict__ ebuf_b, int e, int NB, int NW) {
    __shared__ int base[BKT];
    __shared__ int bump[BKT];
    int l = blockIdx.x / NW, w = blockIdx.x % NW;
    const int* ei = l ? ei_b : ei_a;
    int* ebuf = l ? ebuf_b : ebuf_a;
    if (threadIdx.x < NB) {
        base[threadIdx.x] = boff[l * (NB + 1) + threadIdx.x] +
                            wgoff[((size_t)l * NB + threadIdx.x) * NW + w];
        bump[threadIdx.x] = 0;
    }
    __syncthreads();
    int beg = w * CHUNK, end = min(beg + CHUNK, e);
    for (int j = beg + threadIdx.x; j < end; j += 256) {
        int sv = ei[j], d = ei[e + j];
        int b = d >> 8;
        int pos = base[b] + atomicAdd(&bump[b], 1);
        ebuf[pos] = ((d & 255) << 17) | sv;  // needs src < 2^17
    }
}

// ---------- P4: within-bucket node sort -> final CSR + noff + dinv ----------
__global__ __launch_bounds__(256) void k_p4_nodesort(
    const int* __restrict__ ebuf_a, const int* __restrict__ ebuf_b,
    const int* __restrict__ boff, int* __restrict__ csr_a, int* __restrict__ csr_b,
    int* __restrict__ noff, float* __restrict__ dinv, int n, int e, int NB) {
    __shared__ int hist[256], nstart[256], sc[256];
    int which = blockIdx.x;
    int l = which / NB, b = which - l * NB;
    const int* ebuf = l ? ebuf_b : ebuf_a;
    int* csr = l ? csr_b : csr_a;
    int seg0 = boff[l * (NB + 1) + b], seg1 = boff[l * (NB + 1) + b + 1];
    int t = threadIdx.x;
    hist[t] = 0;
    __syncthreads();
    for (int j = seg0 + t; j < seg1; j += 256) atomicAdd(&hist[ebuf[j] >> 17], 1);
    __syncthreads();
    int v = hist[t];
    sc[t] = v;
    __syncthreads();
    for (int o = 1; o < 256; o <<= 1) {
        int x = 0;
        if (t >= o) x = sc[t - o];
        __syncthreads();
        sc[t] += x;
        __syncthreads();
    }
    nstart[t] = seg0 + sc[t] - v;
    int node = b * BKT + t;
    if (node < n) {
        noff[(size_t)l * (n + 1) + node] = nstart[t];
        dinv[(size_t)l * n + node] = rsqrtf((float)v + 1.0f);
    }
    hist[t] = 0;  // reuse as bump counter
    if (b == NB - 1 && t == 0) noff[(size_t)l * (n + 1) + n] = e;
    __syncthreads();
    for (int j = seg0 + t; j < seg1; j += 256) {
        int pk = ebuf[j];
        int ni = pk >> 17;
        int pos = nstart[ni] + atomicAdd(&hist[ni], 1);
        csr[pos] = pk;  // keep dst&255 in bits 17..24 for the row-owned stream
    }
}

// ---------- fused cvt (x -> per-branch dinv-scaled bf16) + weight packing ----------
__global__ void k_cvt_pack(const float2* __restrict__ x2, const float* __restrict__ dinv,
                           uint* __restrict__ xba, uint* __restrict__ xbb,
                           const float* __restrict__ W0, const float* __restrict__ W1,
                           const float* __restrict__ W2, const float* __restrict__ W3,
                           ushort* __restrict__ Wpb, int n, int cvtb) {
    if ((int)blockIdx.x < cvtb) {
        int i = blockIdx.x * 256 + threadIdx.x;
        if (i >= n * 64) return;
        int node = i >> 6;
        float da = dinv[node], db = dinv[n + node];
        float2 v = x2[i];
        xba[i] = (uint)f2bf(da * v.x) | ((uint)f2bf(da * v.y) << 16);
        xbb[i] = (uint)f2bf(db * v.x) | ((uint)f2bf(db * v.y) << 16);
    } else {
        int i = (blockIdx.x - cvtb) * 256 + threadIdx.x;
        if (i >= 4 * 32768) return;
        int seg = i >> 15;
        int r = i & 32767;
        const float* W = seg == 0 ? W0 : seg == 1 ? W1 : seg == 2 ? W2 : W3;
        int N = seg < 2 ? 256 : 128;
        int k = r / N, nn = r - k * N;
        int kt = k >> 5, q = (k & 31) >> 3, jj = k & 7;
        int nt = nn >> 4, ln = q * 16 + (nn & 15);
        int NT = N >> 4;
        Wpb[(size_t)seg * 32768 + (((size_t)(kt * NT + nt)) * 64 + ln) * 8 + jj] = f2bf(W[r]);
    }
}

// ---------- row-owned edge stream (NO atomics), 8-deep (R10 proven form) ----------
// Wave owns nodes [a0, a1) (<= 8 consecutive, within one 32-row block at
// rowbase). Streams its contiguous dst-sorted CSR range in 8-deep load batches
// crossing node boundaries; register accumulators; plain ds_write flush on
// row change. Each owned row is flushed exactly once (in order), so acc tiles
// need no zero-init. Edge words readfirstlane'd -> scalar row logic.
__device__ inline void wave_stream(const uint* __restrict__ xb, const int* __restrict__ csr,
                                   int ebeg, int eend, int a0, int a1, int lane, int rowbase,
                                   float* __restrict__ accLo, float* __restrict__ accHi) {
    int bkt0 = rowbase & ~255;  // bucket base (blocks never span buckets)
    int cur = a0;
    float ax = 0.f, ay = 0.f;
    int j = ebeg;
    for (; j + 8 <= eend; j += 8) {
        int4 ea = *(const int4*)(csr + j);
        int4 eb = *(const int4*)(csr + j + 4);
        int ew[8];
        ew[0] = __builtin_amdgcn_readfirstlane(ea.x);
        ew[1] = __builtin_amdgcn_readfirstlane(ea.y);
        ew[2] = __builtin_amdgcn_readfirstlane(ea.z);
        ew[3] = __builtin_amdgcn_readfirstlane(ea.w);
        ew[4] = __builtin_amdgcn_readfirstlane(eb.x);
        ew[5] = __builtin_amdgcn_readfirstlane(eb.y);
        ew[6] = __builtin_amdgcn_readfirstlane(eb.z);
        ew[7] = __builtin_amdgcn_readfirstlane(eb.w);
        uint u[8];
#pragma unroll
        for (int k = 0; k < 8; ++k)
            u[k] = xb[(uint)(ew[k] & 0x1ffff) * 64u + lane];
#pragma unroll
        for (int k = 0; k < 8; ++k) {
            int rr = bkt0 | ((ew[k] >> 17) & 255);
            if (rr != cur) {
                accLo[(cur - rowbase) * 64 + lane] = ax;
                accHi[(cur - rowbase) * 64 + lane] = ay;
                for (int c = cur + 1; c < rr; ++c) {
                    accLo[(c - rowbase) * 64 + lane] = 0.f;
                    accHi[(c - rowbase) * 64 + lane] = 0.f;
                }
                cur = rr;
                ax = 0.f;
                ay = 0.f;
            }
            ax += bf2f((ushort)u[k]);
            ay += bf2f((ushort)(u[k] >> 16));
        }
    }
    if (j < eend) {
        int last = eend - 1;
        int ew[8];
        uint u[8];
#pragma unroll
        for (int k = 0; k < 8; ++k) {
            int jj = j + k;
            jj = jj > last ? last : jj;
            ew[k] = __builtin_amdgcn_readfirstlane(csr[jj]);
        }
#pragma unroll
        for (int k = 0; k < 8; ++k)
            u[k] = xb[(uint)(ew[k] & 0x1ffff) * 64u + lane];
#pragma unroll
        for (int k = 0; k < 8; ++k) {
            if (j + k > last) break;  // wave-uniform
            int rr = bkt0 | ((ew[k] >> 17) & 255);
            if (rr != cur) {
                accLo[(cur - rowbase) * 64 + lane] = ax;
                accHi[(cur - rowbase) * 64 + lane] = ay;
                for (int c = cur + 1; c < rr; ++c) {
                    accLo[(c - rowbase) * 64 + lane] = 0.f;
                    accHi[(c - rowbase) * 64 + lane] = 0.f;
                }
                cur = rr;
                ax = 0.f;
                ay = 0.f;
            }
            ax += bf2f((ushort)u[k]);
            ay += bf2f((ushort)(u[k] >> 16));
        }
    }
    // final flush: cur gets the running sums; remaining owned rows get zeros
    accLo[(cur - rowbase) * 64 + lane] = ax;
    accHi[(cur - rowbase) * 64 + lane] = ay;
    for (int c = cur + 1; c < a1; ++c) {
        accLo[(c - rowbase) * 64 + lane] = 0.f;
        accHi[(c - rowbase) * 64 + lane] = 0.f;
    }
}

// ---------- FUSED gather_l1 + MLP ----------
// Block = 32 nodes, 4 waves (8 owned nodes each). XCD-branch partitioning:
// dispatch round-robins bid%8 -> XCD, so group-of-4 parity pins branch a to
// XCDs 0-3 and branch b to XCDs 4-7 (per-XCD table working set 25.6->12.8MB).
// Phase 1: row-owned stream into f32 LDS acc tiles. Finalize:
// A = f2bf(dinv*(acc+self)) with the 16B-block rotation swizzle. Phase 2: MLP.
// LDS aliasing: acc(16K)+hs(16.9K) share [0,16896); A-tile at [16896,25088).
// Total 25088 B -> 6 blocks/CU.
__global__ __launch_bounds__(256) void k_gather_mlp(
    const uint* __restrict__ xba, const uint* __restrict__ xbb,
    const int* __restrict__ csr_a, const int* __restrict__ csr_b,
    const int* __restrict__ noff, const float* __restrict__ dinv,
    const ushort* __restrict__ Wpb, const float* __restrict__ b0,
    const float* __restrict__ b1, ushort* __restrict__ oa, ushort* __restrict__ ob,
    int n, int nblk) {
    constexpr int HW = 264;            // h-tile row stride (ushorts)
    __shared__ uint lds[6272];         // 25088 B
    float* accLo = (float*)lds;        // [32][64] f32, even feats
    float* accHi = (float*)(lds + 2048);  // [32][64] f32, odd feats
    uint* As32 = lds + 4224;           // [32][64] bf16x2 (rotated 16B blocks), 8KB
    ushort* hs = (ushort*)lds;         // [32][264] bf16, aliases acc (acc dead by then)

    // XCD-branch partition: groups of 4 consecutive blocks -> XCDs {0-3} / {4-7}
    int g = blockIdx.x >> 2;
    int br = g & 1;
    int blk = (g >> 1) * 4 + (blockIdx.x & 3);
    if (blk >= nblk) return;  // uniform over the block, before any barrier

    const uint* xb = br ? xbb : xba;
    const int* csr = br ? csr_b : csr_a;
    const int* no = noff + (size_t)br * (n + 1);
    const float* dv = dinv + (size_t)br * n;
    const ushort* W1 = Wpb + (br ? 32768 : 0);
    const ushort* W2 = Wpb + (br ? 3 * 32768 : 2 * 32768);
    const float* bias = br ? b1 : b0;
    ushort* Cout = br ? ob : oa;

    const int t = threadIdx.x;
    const int lane = t & 63;
    const int wave = t >> 6;
    const int l15 = lane & 15;
    const int quad = lane >> 4;
    const int row0 = blk * 32;

    // ---- phase 1: row-owned stream (8 nodes per wave) ----
    {
        int a0 = row0 + wave * 8;
        if (a0 < n) {
            int a1 = min(a0 + 8, n);
            int ebeg = __builtin_amdgcn_readfirstlane(no[a0]);
            int eend = __builtin_amdgcn_readfirstlane(no[a1]);
            wave_stream(xb, csr, ebeg, eend, a0, a1, lane, row0, accLo, accHi);
        }
    }
    __syncthreads();

    // ---- finalize: A[r][f] = f2bf(dinv*(acc + self)), rotated 16B blocks ----
    {
        int r = t >> 3, cb = t & 7;   // row, 16-feat column block
        int node = row0 + r;
        float di = 0.f;
        uint4 s0 = (uint4){0, 0, 0, 0}, s1 = (uint4){0, 0, 0, 0};
        if (node < n) {
            di = dv[node];
            const uint4* xp = (const uint4*)(xb + (size_t)node * 64 + cb * 8);
            s0 = xp[0];
            s1 = xp[1];
        }
        const float* aL = accLo + r * 64 + cb * 8;
        const float* aH = accHi + r * 64 + cb * 8;
        uint us[8];
        us[0] = s0.x; us[1] = s0.y; us[2] = s0.z; us[3] = s0.w;
        us[4] = s1.x; us[5] = s1.y; us[6] = s1.z; us[7] = s1.w;
        uint dw[8];
#pragma unroll
        for (int k = 0; k < 8; ++k) {
            float lo = (node < n) ? di * (aL[k] + bf2f((ushort)us[k])) : 0.f;
            float hi = (node < n) ? di * (aH[k] + bf2f((ushort)(us[k] >> 16))) : 0.f;
            dw[k] = (uint)f2bf(lo) | ((uint)f2bf(hi) << 16);
        }
        int b0i = cb * 2;
        *(uint4*)&As32[r * 64 + ((b0i + r) & 15) * 4] = (uint4){dw[0], dw[1], dw[2], dw[3]};
        *(uint4*)&As32[r * 64 + ((b0i + 1 + r) & 15) * 4] = (uint4){dw[4], dw[5], dw[6], dw[7]};
    }
    __syncthreads();

    // ---- phase 2a: h[32x64 cols @ wave*64] = relu(A@W1 + b) ----
    {
        f4_t acc[2][4];
#pragma unroll
        for (int a = 0; a < 2; ++a)
#pragma unroll
            for (int b = 0; b < 4; ++b) acc[a][b] = (f4_t){0.f, 0.f, 0.f, 0.f};

#pragma unroll
        for (int kt = 0; kt < 4; ++kt) {
            bf8_t af[2];
#pragma unroll
            for (int mi = 0; mi < 2; ++mi) {
                int rr = mi * 16 + l15;
                int blk16 = (kt * 4 + quad + rr) & 15;  // un-rotate
                af[mi] = *(const bf8_t*)&As32[rr * 64 + blk16 * 4];
            }
#pragma unroll
            for (int nj = 0; nj < 4; ++nj) {
                int nt = wave * 4 + nj;
                bf8_t wf = *(const bf8_t*)(W1 + (((size_t)(kt * 16 + nt)) * 64 + lane) * 8);
#pragma unroll
                for (int mi = 0; mi < 2; ++mi)
                    acc[mi][nj] = __builtin_amdgcn_mfma_f32_16x16x32_bf16(af[mi], wf, acc[mi][nj], 0, 0, 0);
            }
        }
#pragma unroll
        for (int nj = 0; nj < 4; ++nj) {
            int col = wave * 64 + nj * 16 + l15;
            float bv = bias[col];
#pragma unroll
            for (int mi = 0; mi < 2; ++mi)
#pragma unroll
                for (int r = 0; r < 4; ++r)
                    hs[(mi * 16 + quad * 4 + r) * HW + col] = f2bf(fmaxf(acc[mi][nj][r] + bv, 0.f));
        }
    }
    __syncthreads();

    // ---- phase 2b: C[32x32 cols @ wave*32] = (h@W2)*dinv ----
    {
        f4_t acc2[2][2];
#pragma unroll
        for (int a = 0; a < 2; ++a)
#pragma unroll
            for (int b = 0; b < 2; ++b) acc2[a][b] = (f4_t){0.f, 0.f, 0.f, 0.f};

#pragma unroll
        for (int kt = 0; kt < 8; ++kt) {
            bf8_t af[2];
#pragma unroll
            for (int mi = 0; mi < 2; ++mi)
                af[mi] = *(const bf8_t*)&hs[(mi * 16 + l15) * HW + kt * 32 + quad * 8];
#pragma unroll
            for (int nj = 0; nj < 2; ++nj) {
                int nt = wave * 2 + nj;
                bf8_t wf = *(const bf8_t*)(W2 + (((size_t)(kt * 8 + nt)) * 64 + lane) * 8);
#pragma unroll
                for (int mi = 0; mi < 2; ++mi)
                    acc2[mi][nj] = __builtin_amdgcn_mfma_f32_16x16x32_bf16(af[mi], wf, acc2[mi][nj], 0, 0, 0);
            }
        }
#pragma unroll
        for (int nj = 0; nj < 2; ++nj) {
            int col = wave * 32 + nj * 16 + l15;
#pragma unroll
            for (int mi = 0; mi < 2; ++mi)
#pragma unroll
                for (int r = 0; r < 4; ++r) {
                    int row = row0 + mi * 16 + quad * 4 + r;
                    if (row < n)
                        Cout[(size_t)row * 128 + col] = f2bf(acc2[mi][nj][r] * dv[row]);
                }
        }
    }
}

// ---------- gather_l2: 32-node blocks, both branches via row-owned streams ----------
// LDS = 4 x [32][64] f32 = 32 KB -> 5 blocks/CU. All blocks stream table A
// then table B (phase-aligned -> ~12.8MB working set already). Finalize fuses
// self terms, dinv scaling, bias (b2+b3) and the float32 output store.
__global__ __launch_bounds__(256) void k_gather_l2(
    const uint* __restrict__ hba, const uint* __restrict__ hbb,
    const int* __restrict__ csr_a, const int* __restrict__ csr_b,
    const int* __restrict__ noff, const float* __restrict__ dinv,
    const float* __restrict__ b2, const float* __restrict__ b3,
    float* __restrict__ out, int n) {
    __shared__ uint lds[8192];  // 32 KB
    float* aLoA = (float*)lds;
    float* aHiA = (float*)(lds + 2048);
    float* aLoB = (float*)(lds + 4096);
    float* aHiB = (float*)(lds + 6144);

    const int t = threadIdx.x;
    const int lane = t & 63;
    const int wave = t >> 6;
    const int row0 = blockIdx.x * 32;

    {
        int a0 = row0 + wave * 8;
        if (a0 < n) {
            int a1 = min(a0 + 8, n);
            int ebeg = __builtin_amdgcn_readfirstlane(noff[a0]);
            int eend = __builtin_amdgcn_readfirstlane(noff[a1]);
            wave_stream(hba, csr_a, ebeg, eend, a0, a1, lane, row0, aLoA, aHiA);
            const int* no_b = noff + (n + 1);
            int ebeg2 = __builtin_amdgcn_readfirstlane(no_b[a0]);
            int eend2 = __builtin_amdgcn_readfirstlane(no_b[a1]);
            wave_stream(hbb, csr_b, ebeg2, eend2, a0, a1, lane, row0, aLoB, aHiB);
        }
    }
    __syncthreads();

    int r = t >> 3, cb = t & 7;
    int node = row0 + r;
    if (node >= n) return;
    float fa = dinv[node], fb = dinv[n + node];
    const uint4* xa = (const uint4*)(hba + (size_t)node * 64 + cb * 8);
    const uint4* xbp = (const uint4*)(hbb + (size_t)node * 64 + cb * 8);
    uint4 a0v = xa[0], a1v = xa[1];
    uint4 c0 = xbp[0], c1 = xbp[1];
    uint ua[8], ub[8];
    ua[0] = a0v.x; ua[1] = a0v.y; ua[2] = a0v.z; ua[3] = a0v.w;
    ua[4] = a1v.x; ua[5] = a1v.y; ua[6] = a1v.z; ua[7] = a1v.w;
    ub[0] = c0.x; ub[1] = c0.y; ub[2] = c0.z; ub[3] = c0.w;
    ub[4] = c1.x; ub[5] = c1.y; ub[6] = c1.z; ub[7] = c1.w;

    const float4* b2v = (const float4*)(b2 + cb * 16);
    const float4* b3v = (const float4*)(b3 + cb * 16);
    const float* aLA = aLoA + r * 64 + cb * 8;
    const float* aHA = aHiA + r * 64 + cb * 8;
    const float* aLB = aLoB + r * 64 + cb * 8;
    const float* aHB = aHiB + r * 64 + cb * 8;

    float res[16];
#pragma unroll
    for (int k = 0; k < 8; ++k) {
        res[2 * k] = fa * (aLA[k] + bf2f((ushort)ua[k])) +
                     fb * (aLB[k] + bf2f((ushort)ub[k]));
        res[2 * k + 1] = fa * (aHA[k] + bf2f((ushort)(ua[k] >> 16))) +
                         fb * (aHB[k] + bf2f((ushort)(ub[k] >> 16)));
    }
    float4* op = (float4*)(out + (size_t)node * 128 + cb * 16);
#pragma unroll
    for (int i = 0; i < 4; ++i) {
        float4 bsum2 = b2v[i];
        float4 bsum3 = b3v[i];
        float4 o;
        o.x = res[4 * i + 0] + bsum2.x + bsum3.x;
        o.y = res[4 * i + 1] + bsum2.y + bsum3.y;
        o.z = res[4 * i + 2] + bsum2.z + bsum3.z;
        o.w = res[4 * i + 3] + bsum2.w + bsum3.w;
        op[i] = o;
    }
}

extern "C" void kernel_launch(void* const* d_in, const int* in_sizes, int n_in,
                              void* d_out, int out_size, void* d_ws, size_t ws_size,
                              hipStream_t stream) {
    const float* x    = (const float*)d_in[0];
    const int*   ei_a = (const int*)d_in[1];
    const int*   ei_b = (const int*)d_in[2];
    const float* W0 = (const float*)d_in[3];
    const float* b0 = (const float*)d_in[4];
    const float* W1 = (const float*)d_in[5];
    const float* b1 = (const float*)d_in[6];
    const float* W2 = (const float*)d_in[7];
    const float* b2 = (const float*)d_in[8];
    const float* W3 = (const float*)d_in[9];
    const float* b3 = (const float*)d_in[10];
    float* out = (float*)d_out;

    const int n = in_sizes[0] / 128;  // 50000 (< 2^17)
    const int e = in_sizes[1] / 2;    // 800000
    const int NB = (n + BKT - 1) / BKT;      // 196 (<= 256)
    const int NW = (e + CHUNK - 1) / CHUNK;  // 196 (<= 256)

    // workspace (~92 MB)
    float*  ws   = (float*)d_ws;
    float*  dinv = ws;                                // 2n
    uint*   xba  = (uint*)(ws + 2 * (size_t)n);       // 64n
    uint*   xbb  = xba + 64 * (size_t)n;              // 64n
    uint*   oa   = xbb + 64 * (size_t)n;              // 64n (bf16 g, branch a)
    uint*   ob   = oa + 64 * (size_t)n;               // 64n
    ushort* Wpb  = (ushort*)(ob + 64 * (size_t)n);    // 4*32768 ushort
    int* cnt_mat = (int*)(Wpb + 4 * 32768);           // 2*NW*NB
    int* wgoff   = cnt_mat + 2 * (size_t)NW * NB;     // 2*NB*NW
    int* btot    = wgoff + 2 * (size_t)NB * NW;       // 2*NB
    int* boff    = btot + 2 * NB;                     // 2*(NB+1)
    int* noff    = boff + 2 * (NB + 1);               // 2*(n+1)
    int* ebuf_a  = noff + 2 * (n + 1);                // e
    int* ebuf_b  = ebuf_a + e;                        // e
    int* csr_a   = ebuf_b + e;                        // e
    int* csr_b   = csr_a + e;                         // e

    const int B = 256;

    // --- CSR build (atomic-free) ---
    k_p1_hist<<<2 * NW, B, 0, stream>>>(ei_a, ei_b, cnt_mat, e, NB, NW);
    k_p2a<<<2 * NB, B, 0, stream>>>(cnt_mat, wgoff, btot, NB, NW);
    k_p2b<<<1, B, 0, stream>>>(btot, boff, NB, e);
    k_p3_scatter<<<2 * NW, B, 0, stream>>>(ei_a, ei_b, wgoff, boff, ebuf_a, ebuf_b, e, NB, NW);
    k_p4_nodesort<<<2 * NB, B, 0, stream>>>(ebuf_a, ebuf_b, boff, csr_a, csr_b, noff, dinv,
                                            n, e, NB);

    // --- conversions (fused cvt + weight pack) ---
    const int cvtb = (n * 64 + B - 1) / B;
    const int packb = (4 * 32768 + B - 1) / B;
    k_cvt_pack<<<cvtb + packb, B, 0, stream>>>((const float2*)x, dinv, xba, xbb,
                                               W0, W1, W2, W3, Wpb, n, cvtb);

    // --- fused layer-1 gather + MLP, both branches, XCD-branch partitioned ---
    const int nblk = (n + 31) / 32;
    const int grp4 = (nblk + 3) / 4;   // groups of 4 blocks; 2 branches alternate
    k_gather_mlp<<<grp4 * 8, B, 0, stream>>>(xba, xbb, csr_a, csr_b, noff, dinv, Wpb,
                                             b0, b1, (ushort*)oa, (ushort*)ob, n, nblk);

    // --- layer-2 aggregation + ensemble sum + bias (row-owned stream blocks) ---
    k_gather_l2<<<nblk, B, 0, stream>>>(oa, ob, csr_a, csr_b, noff, dinv, b2, b3, out, n);
}

// Round 5
// 277.640 us; speedup vs baseline: 1.5576x; 1.0441x over previous
//
#include <hip/hip_runtime.h>

// GCN ensemble: atomic-free counting-sort CSR (256-node buckets) + FUSED
// (gather_l1 + MLP) kernel + gather_l2.
// R13: occupancy lever. R12 counters: nothing saturated (VALU 33%, HBM 29%,
// Mfma 6%) but OccupancyPercent 44% with LDS 25088B capping at 6 blocks/CU.
// Latency-bound gather throughput ~ resident waves, so cut LDS:
//  - k_gather_mlp: A-tile ALIASES the (dead) accLo region after finalize
//    reads acc into regs (2 extra barriers). 25088 -> 16896 B -> 8 blocks/CU.
//  - k_gather_l2: stream branch A -> fold into reg partials res[16] ->
//    barrier -> REUSE the same 16KB acc tiles for branch B. 32KB -> 16KB.
// Keeps R12's XCD-branch partitioning (A/B: FETCH -5%, dur -2%).
// Math unchanged: agg[d] = dinv_d * (sum_s g[s] + g[d]), g = dinv*h (bf16).

typedef unsigned int uint;
typedef unsigned short ushort;
typedef __attribute__((ext_vector_type(8))) short bf8_t;
typedef __attribute__((ext_vector_type(4))) float f4_t;

#define CHUNK 4096   // edges per WG in P1/P3; NW = ceil(e/CHUNK) <= 256
#define BKT 256      // nodes per bucket; NB = ceil(n/256) <= 256, needs n < 2^17

__device__ inline ushort f2bf(float f) {
    uint u = __float_as_uint(f);
    return (ushort)((u + 0x7fff + ((u >> 16) & 1)) >> 16);
}
__device__ inline float bf2f(ushort h) { return __uint_as_float(((uint)h) << 16); }

// ---------- P1: per-chunk bucket histogram (LDS), dense writes ----------
__global__ __launch_bounds__(256) void k_p1_hist(
    const int* __restrict__ ei_a, const int* __restrict__ ei_b,
    int* __restrict__ cnt_mat, int e, int NB, int NW) {
    __shared__ int lh[BKT];
    int l = blockIdx.x / NW, w = blockIdx.x % NW;
    const int* dst = (l ? ei_b : ei_a) + e;
    if (threadIdx.x < NB) lh[threadIdx.x] = 0;
    __syncthreads();
    int beg = w * CHUNK, end = min(beg + CHUNK, e);
    for (int j = beg + threadIdx.x; j < end; j += 256) atomicAdd(&lh[dst[j] >> 8], 1);
    __syncthreads();
    int* outp = cnt_mat + ((size_t)l * NW + w) * NB;
    if (threadIdx.x < NB) outp[threadIdx.x] = lh[threadIdx.x];
}

// ---------- P2a: per-bucket exclusive prefix over WGs (one block per bucket) ----------
__global__ __launch_bounds__(256) void k_p2a(const int* __restrict__ cnt_mat,
                                             int* __restrict__ wgoff, int* __restrict__ btot,
                                             int NB, int NW) {
    __shared__ int s[256];
    int which = blockIdx.x;  // 0..2*NB-1
    int l = which / NB, b = which - l * NB;
    int t = threadIdx.x;
    int v = (t < NW) ? cnt_mat[((size_t)l * NW + t) * NB + b] : 0;
    s[t] = v;
    __syncthreads();
    for (int o = 1; o < 256; o <<= 1) {
        int x = 0;
        if (t >= o) x = s[t - o];
        __syncthreads();
        s[t] += x;
        __syncthreads();
    }
    if (t < NW) wgoff[((size_t)l * NB + b) * NW + t] = s[t] - v;
    if (t == 255) btot[which] = s[255];
}

// ---------- P2b: exclusive scan of bucket totals per list (one WG, NB<=256) ----------
__global__ __launch_bounds__(256) void k_p2b(const int* __restrict__ btot,
                                             int* __restrict__ boff, int NB, int e) {
    __shared__ int s[256];
    for (int l = 0; l < 2; ++l) {
        int t = threadIdx.x;
        int v = (t < NB) ? btot[l * NB + t] : 0;
        s[t] = v;
        __syncthreads();
        for (int o = 1; o < 256; o <<= 1) {
            int x = 0;
            if (t >= o) x = s[t - o];
            __syncthreads();
            s[t] += x;
            __syncthreads();
        }
        if (t < NB) boff[l * (NB + 1) + t] = s[t] - v;
        if (t == 0) boff[l * (NB + 1) + NB] = e;
        __syncthreads();
    }
}

// ---------- P3: scatter packed entries into contiguous per-(WG,bucket) segments ----------
__global__ __launch_bounds__(256) void k_p3_scatter(
    const int* __restrict__ ei_a, const int* __restrict__ ei_b,
    const int* __restrict__ wgoff, const int* __restrict__ boff,
    int* __restrict__ ebuf_a, int* __restrict__ ebuf_b, int e, int NB, int NW) {
    __shared__ int base[BKT];
    __shared__ int bump[BKT];
    int l = blockIdx.x / NW, w = blockIdx.x % NW;
    const int* ei = l ? ei_b : ei_a;
    int* ebuf = l ? ebuf_b : ebuf_a;
    if (threadIdx.x < NB) {
        base[threadIdx.x] = boff[l * (NB + 1) + threadIdx.x] +
                            wgoff[((size_t)l * NB + threadIdx.x) * NW + w];
        bump[threadIdx.x] = 0;
    }
    __syncthreads();
    int beg = w * CHUNK, end = min(beg + CHUNK, e);
    for (int j = beg + threadIdx.x; j < end; j += 256) {
        int sv = ei[j], d = ei[e + j];
        int b = d >> 8;
        int pos = base[b] + atomicAdd(&bump[b], 1);
        ebuf[pos] = ((d & 255) << 17) | sv;  // needs src < 2^17
    }
}

// ---------- P4: within-bucket node sort -> final CSR + noff + dinv ----------
__global__ __launch_bounds__(256) void k_p4_nodesort(
    const int* __restrict__ ebuf_a, const int* __restrict__ ebuf_b,
    const int* __restrict__ boff, int* __restrict__ csr_a, int* __restrict__ csr_b,
    int* __restrict__ noff, float* __restrict__ dinv, int n, int e, int NB) {
    __shared__ int hist[256], nstart[256], sc[256];
    int which = blockIdx.x;
    int l = which / NB, b = which - l * NB;
    const int* ebuf = l ? ebuf_b : ebuf_a;
    int* csr = l ? csr_b : csr_a;
    int seg0 = boff[l * (NB + 1) + b], seg1 = boff[l * (NB + 1) + b + 1];
    int t = threadIdx.x;
    hist[t] = 0;
    __syncthreads();
    for (int j = seg0 + t; j < seg1; j += 256) atomicAdd(&hist[ebuf[j] >> 17], 1);
    __syncthreads();
    int v = hist[t];
    sc[t] = v;
    __syncthreads();
    for (int o = 1; o < 256; o <<= 1) {
        int x = 0;
        if (t >= o) x = sc[t - o];
        __syncthreads();
        sc[t] += x;
        __syncthreads();
    }
    nstart[t] = seg0 + sc[t] - v;
    int node = b * BKT + t;
    if (node < n) {
        noff[(size_t)l * (n + 1) + node] = nstart[t];
        dinv[(size_t)l * n + node] = rsqrtf((float)v + 1.0f);
    }
    hist[t] = 0;  // reuse as bump counter
    if (b == NB - 1 && t == 0) noff[(size_t)l * (n + 1) + n] = e;
    __syncthreads();
    for (int j = seg0 + t; j < seg1; j += 256) {
        int pk = ebuf[j];
        int ni = pk >> 17;
        int pos = nstart[ni] + atomicAdd(&hist[ni], 1);
        csr[pos] = pk;  // keep dst&255 in bits 17..24 for the row-owned stream
    }
}

// ---------- fused cvt (x -> per-branch dinv-scaled bf16) + weight packing ----------
__global__ void k_cvt_pack(const float2* __restrict__ x2, const float* __restrict__ dinv,
                           uint* __restrict__ xba, uint* __restrict__ xbb,
                           const float* __restrict__ W0, const float* __restrict__ W1,
                           const float* __restrict__ W2, const float* __restrict__ W3,
                           ushort* __restrict__ Wpb, int n, int cvtb) {
    if ((int)blockIdx.x < cvtb) {
        int i = blockIdx.x * 256 + threadIdx.x;
        if (i >= n * 64) return;
        int node = i >> 6;
        float da = dinv[node], db = dinv[n + node];
        float2 v = x2[i];
        xba[i] = (uint)f2bf(da * v.x) | ((uint)f2bf(da * v.y) << 16);
        xbb[i] = (uint)f2bf(db * v.x) | ((uint)f2bf(db * v.y) << 16);
    } else {
        int i = (blockIdx.x - cvtb) * 256 + threadIdx.x;
        if (i >= 4 * 32768) return;
        int seg = i >> 15;
        int r = i & 32767;
        const float* W = seg == 0 ? W0 : seg == 1 ? W1 : seg == 2 ? W2 : W3;
        int N = seg < 2 ? 256 : 128;
        int k = r / N, nn = r - k * N;
        int kt = k >> 5, q = (k & 31) >> 3, jj = k & 7;
        int nt = nn >> 4, ln = q * 16 + (nn & 15);
        int NT = N >> 4;
        Wpb[(size_t)seg * 32768 + (((size_t)(kt * NT + nt)) * 64 + ln) * 8 + jj] = f2bf(W[r]);
    }
}

// ---------- row-owned edge stream (NO atomics), 8-deep (R10 proven form) ----------
// Wave owns nodes [a0, a1) (<= 8 consecutive, within one 32-row block at
// rowbase). Streams its contiguous dst-sorted CSR range in 8-deep load batches
// crossing node boundaries; register accumulators; plain ds_write flush on
// row change. Each owned row is flushed exactly once (in order), so acc tiles
// need no zero-init. Edge words readfirstlane'd -> scalar row logic.
__device__ inline void wave_stream(const uint* __restrict__ xb, const int* __restrict__ csr,
                                   int ebeg, int eend, int a0, int a1, int lane, int rowbase,
                                   float* __restrict__ accLo, float* __restrict__ accHi) {
    int bkt0 = rowbase & ~255;  // bucket base (blocks never span buckets)
    int cur = a0;
    float ax = 0.f, ay = 0.f;
    int j = ebeg;
    for (; j + 8 <= eend; j += 8) {
        int4 ea = *(const int4*)(csr + j);
        int4 eb = *(const int4*)(csr + j + 4);
        int ew[8];
        ew[0] = __builtin_amdgcn_readfirstlane(ea.x);
        ew[1] = __builtin_amdgcn_readfirstlane(ea.y);
        ew[2] = __builtin_amdgcn_readfirstlane(ea.z);
        ew[3] = __builtin_amdgcn_readfirstlane(ea.w);
        ew[4] = __builtin_amdgcn_readfirstlane(eb.x);
        ew[5] = __builtin_amdgcn_readfirstlane(eb.y);
        ew[6] = __builtin_amdgcn_readfirstlane(eb.z);
        ew[7] = __builtin_amdgcn_readfirstlane(eb.w);
        uint u[8];
#pragma unroll
        for (int k = 0; k < 8; ++k)
            u[k] = xb[(uint)(ew[k] & 0x1ffff) * 64u + lane];
#pragma unroll
        for (int k = 0; k < 8; ++k) {
            int rr = bkt0 | ((ew[k] >> 17) & 255);
            if (rr != cur) {
                accLo[(cur - rowbase) * 64 + lane] = ax;
                accHi[(cur - rowbase) * 64 + lane] = ay;
                for (int c = cur + 1; c < rr; ++c) {
                    accLo[(c - rowbase) * 64 + lane] = 0.f;
                    accHi[(c - rowbase) * 64 + lane] = 0.f;
                }
                cur = rr;
                ax = 0.f;
                ay = 0.f;
            }
            ax += bf2f((ushort)u[k]);
            ay += bf2f((ushort)(u[k] >> 16));
        }
    }
    if (j < eend) {
        int last = eend - 1;
        int ew[8];
        uint u[8];
#pragma unroll
        for (int k = 0; k < 8; ++k) {
            int jj = j + k;
            jj = jj > last ? last : jj;
            ew[k] = __builtin_amdgcn_readfirstlane(csr[jj]);
        }
#pragma unroll
        for (int k = 0; k < 8; ++k)
            u[k] = xb[(uint)(ew[k] & 0x1ffff) * 64u + lane];
#pragma unroll
        for (int k = 0; k < 8; ++k) {
            if (j + k > last) break;  // wave-uniform
            int rr = bkt0 | ((ew[k] >> 17) & 255);
            if (rr != cur) {
                accLo[(cur - rowbase) * 64 + lane] = ax;
                accHi[(cur - rowbase) * 64 + lane] = ay;
                for (int c = cur + 1; c < rr; ++c) {
                    accLo[(c - rowbase) * 64 + lane] = 0.f;
                    accHi[(c - rowbase) * 64 + lane] = 0.f;
                }
                cur = rr;
                ax = 0.f;
                ay = 0.f;
            }
            ax += bf2f((ushort)u[k]);
            ay += bf2f((ushort)(u[k] >> 16));
        }
    }
    // final flush: cur gets the running sums; remaining owned rows get zeros
    accLo[(cur - rowbase) * 64 + lane] = ax;
    accHi[(cur - rowbase) * 64 + lane] = ay;
    for (int c = cur + 1; c < a1; ++c) {
        accLo[(c - rowbase) * 64 + lane] = 0.f;
        accHi[(c - rowbase) * 64 + lane] = 0.f;
    }
}

// ---------- FUSED gather_l1 + MLP ----------
// Block = 32 nodes, 4 waves (8 owned nodes each). XCD-branch partitioning
// (R12 A/B: FETCH -5%). LDS = 16896 B total: acc tiles [0,16384); the 8KB
// A-tile ALIASES [0,8192) (acc dead after finalize reads -> regs); hs
// [32][264] spans [0,16896). Barriers: stream | finalize-read | As32-write |
// mfma-read | hs-write | phase2b. 16896 B -> 8 blocks/CU (wave cap).
__global__ __launch_bounds__(256) void k_gather_mlp(
    const uint* __restrict__ xba, const uint* __restrict__ xbb,
    const int* __restrict__ csr_a, const int* __restrict__ csr_b,
    const int* __restrict__ noff, const float* __restrict__ dinv,
    const ushort* __restrict__ Wpb, const float* __restrict__ b0,
    const float* __restrict__ b1, ushort* __restrict__ oa, ushort* __restrict__ ob,
    int n, int nblk) {
    constexpr int HW = 264;            // h-tile row stride (ushorts)
    __shared__ uint lds[4224];         // 16896 B
    float* accLo = (float*)lds;        // [32][64] f32 @ [0,8192)
    float* accHi = (float*)(lds + 2048);  // [32][64] f32 @ [8192,16384)
    uint* As32 = lds;                  // [32][64] bf16x2 @ [0,8192), aliases accLo
    ushort* hs = (ushort*)lds;         // [32][264] bf16 @ [0,16896)

    // XCD-branch partition: groups of 4 consecutive blocks -> XCDs {0-3} / {4-7}
    int g = blockIdx.x >> 2;
    int br = g & 1;
    int blk = (g >> 1) * 4 + (blockIdx.x & 3);
    if (blk >= nblk) return;  // uniform over the block, before any barrier

    const uint* xb = br ? xbb : xba;
    const int* csr = br ? csr_b : csr_a;
    const int* no = noff + (size_t)br * (n + 1);
    const float* dv = dinv + (size_t)br * n;
    const ushort* W1 = Wpb + (br ? 32768 : 0);
    const ushort* W2 = Wpb + (br ? 3 * 32768 : 2 * 32768);
    const float* bias = br ? b1 : b0;
    ushort* Cout = br ? ob : oa;

    const int t = threadIdx.x;
    const int lane = t & 63;
    const int wave = t >> 6;
    const int l15 = lane & 15;
    const int quad = lane >> 4;
    const int row0 = blk * 32;

    // ---- phase 1: row-owned stream (8 nodes per wave) ----
    {
        int a0 = row0 + wave * 8;
        if (a0 < n) {
            int a1 = min(a0 + 8, n);
            int ebeg = __builtin_amdgcn_readfirstlane(no[a0]);
            int eend = __builtin_amdgcn_readfirstlane(no[a1]);
            wave_stream(xb, csr, ebeg, eend, a0, a1, lane, row0, accLo, accHi);
        }
    }
    __syncthreads();

    // ---- finalize (read half): A[r][f] = f2bf(dinv*(acc + self)) -> regs ----
    uint dw[8];
    {
        int r = t >> 3, cb = t & 7;   // row, 16-feat column block
        int node = row0 + r;
        float di = 0.f;
        uint4 s0 = (uint4){0, 0, 0, 0}, s1 = (uint4){0, 0, 0, 0};
        if (node < n) {
            di = dv[node];
            const uint4* xp = (const uint4*)(xb + (size_t)node * 64 + cb * 8);
            s0 = xp[0];
            s1 = xp[1];
        }
        const float* aL = accLo + r * 64 + cb * 8;
        const float* aH = accHi + r * 64 + cb * 8;
        uint us[8];
        us[0] = s0.x; us[1] = s0.y; us[2] = s0.z; us[3] = s0.w;
        us[4] = s1.x; us[5] = s1.y; us[6] = s1.z; us[7] = s1.w;
#pragma unroll
        for (int k = 0; k < 8; ++k) {
            float lo = (node < n) ? di * (aL[k] + bf2f((ushort)us[k])) : 0.f;
            float hi = (node < n) ? di * (aH[k] + bf2f((ushort)(us[k] >> 16))) : 0.f;
            dw[k] = (uint)f2bf(lo) | ((uint)f2bf(hi) << 16);
        }
    }
    __syncthreads();  // all acc reads done; As32 may now overwrite [0,8192)

    // ---- finalize (write half): rotated 16B blocks into As32 ----
    {
        int r = t >> 3, cb = t & 7;
        int b0i = cb * 2;
        *(uint4*)&As32[r * 64 + ((b0i + r) & 15) * 4] = (uint4){dw[0], dw[1], dw[2], dw[3]};
        *(uint4*)&As32[r * 64 + ((b0i + 1 + r) & 15) * 4] = (uint4){dw[4], dw[5], dw[6], dw[7]};
    }
    __syncthreads();

    // ---- phase 2a: h[32x64 cols @ wave*64] = relu(A@W1 + b) ----
    {
        f4_t acc[2][4];
#pragma unroll
        for (int a = 0; a < 2; ++a)
#pragma unroll
            for (int b = 0; b < 4; ++b) acc[a][b] = (f4_t){0.f, 0.f, 0.f, 0.f};

#pragma unroll
        for (int kt = 0; kt < 4; ++kt) {
            bf8_t af[2];
#pragma unroll
            for (int mi = 0; mi < 2; ++mi) {
                int rr = mi * 16 + l15;
                int blk16 = (kt * 4 + quad + rr) & 15;  // un-rotate
                af[mi] = *(const bf8_t*)&As32[rr * 64 + blk16 * 4];
            }
#pragma unroll
            for (int nj = 0; nj < 4; ++nj) {
                int nt = wave * 4 + nj;
                bf8_t wf = *(const bf8_t*)(W1 + (((size_t)(kt * 16 + nt)) * 64 + lane) * 8);
#pragma unroll
                for (int mi = 0; mi < 2; ++mi)
                    acc[mi][nj] = __builtin_amdgcn_mfma_f32_16x16x32_bf16(af[mi], wf, acc[mi][nj], 0, 0, 0);
            }
        }
        __syncthreads();  // all As32 reads done; hs may now overwrite [0,16896)
#pragma unroll
        for (int nj = 0; nj < 4; ++nj) {
            int col = wave * 64 + nj * 16 + l15;
            float bv = bias[col];
#pragma unroll
            for (int mi = 0; mi < 2; ++mi)
#pragma unroll
                for (int r = 0; r < 4; ++r)
                    hs[(mi * 16 + quad * 4 + r) * HW + col] = f2bf(fmaxf(acc[mi][nj][r] + bv, 0.f));
        }
    }
    __syncthreads();

    // ---- phase 2b: C[32x32 cols @ wave*32] = (h@W2)*dinv ----
    {
        f4_t acc2[2][2];
#pragma unroll
        for (int a = 0; a < 2; ++a)
#pragma unroll
            for (int b = 0; b < 2; ++b) acc2[a][b] = (f4_t){0.f, 0.f, 0.f, 0.f};

#pragma unroll
        for (int kt = 0; kt < 8; ++kt) {
            bf8_t af[2];
#pragma unroll
            for (int mi = 0; mi < 2; ++mi)
                af[mi] = *(const bf8_t*)&hs[(mi * 16 + l15) * HW + kt * 32 + quad * 8];
#pragma unroll
            for (int nj = 0; nj < 2; ++nj) {
                int nt = wave * 2 + nj;
                bf8_t wf = *(const bf8_t*)(W2 + (((size_t)(kt * 8 + nt)) * 64 + lane) * 8);
#pragma unroll
                for (int mi = 0; mi < 2; ++mi)
                    acc2[mi][nj] = __builtin_amdgcn_mfma_f32_16x16x32_bf16(af[mi], wf, acc2[mi][nj], 0, 0, 0);
            }
        }
#pragma unroll
        for (int nj = 0; nj < 2; ++nj) {
            int col = wave * 32 + nj * 16 + l15;
#pragma unroll
            for (int mi = 0; mi < 2; ++mi)
#pragma unroll
                for (int r = 0; r < 4; ++r) {
                    int row = row0 + mi * 16 + quad * 4 + r;
                    if (row < n)
                        Cout[(size_t)row * 128 + col] = f2bf(acc2[mi][nj][r] * dv[row]);
                }
        }
    }
}

// ---------- gather_l2: 32-node blocks; branches A,B time-share ONE 16KB acc ----------
// Stream A -> fold into reg partials res[16] (self+dinv applied) -> barrier ->
// stream B into the SAME tiles -> finalize adds branch B + bias, stores f32.
// LDS 16384 B -> wave-cap occupancy (was 32KB -> 5 blocks/CU).
__global__ __launch_bounds__(256) void k_gather_l2(
    const uint* __restrict__ hba, const uint* __restrict__ hbb,
    const int* __restrict__ csr_a, const int* __restrict__ csr_b,
    const int* __restrict__ noff, const float* __restrict__ dinv,
    const float* __restrict__ b2, const float* __restrict__ b3,
    float* __restrict__ out, int n) {
    __shared__ uint lds[4096];  // 16 KB
    float* aLo = (float*)lds;
    float* aHi = (float*)(lds + 2048);

    const int t = threadIdx.x;
    const int lane = t & 63;
    const int wave = t >> 6;
    const int row0 = blockIdx.x * 32;
    const int r = t >> 3, cb = t & 7;
    const int node = row0 + r;

    // ---- stream branch A ----
    {
        int a0 = row0 + wave * 8;
        if (a0 < n) {
            int a1 = min(a0 + 8, n);
            int ebeg = __builtin_amdgcn_readfirstlane(noff[a0]);
            int eend = __builtin_amdgcn_readfirstlane(noff[a1]);
            wave_stream(hba, csr_a, ebeg, eend, a0, a1, lane, row0, aLo, aHi);
        }
    }
    __syncthreads();

    // ---- fold branch A into register partials ----
    float res[16];
    if (node < n) {
        float fa = dinv[node];
        const uint4* xa = (const uint4*)(hba + (size_t)node * 64 + cb * 8);
        uint4 a0v = xa[0], a1v = xa[1];
        uint ua[8];
        ua[0] = a0v.x; ua[1] = a0v.y; ua[2] = a0v.z; ua[3] = a0v.w;
        ua[4] = a1v.x; ua[5] = a1v.y; ua[6] = a1v.z; ua[7] = a1v.w;
        const float* aLA = aLo + r * 64 + cb * 8;
        const float* aHA = aHi + r * 64 + cb * 8;
#pragma unroll
        for (int k = 0; k < 8; ++k) {
            res[2 * k] = fa * (aLA[k] + bf2f((ushort)ua[k]));
            res[2 * k + 1] = fa * (aHA[k] + bf2f((ushort)(ua[k] >> 16)));
        }
    } else {
#pragma unroll
        for (int k = 0; k < 16; ++k) res[k] = 0.f;
    }
    __syncthreads();  // all A reads done; tiles free for branch B

    // ---- stream branch B into the same tiles ----
    {
        int a0 = row0 + wave * 8;
        if (a0 < n) {
            int a1 = min(a0 + 8, n);
            const int* no_b = noff + (n + 1);
            int ebeg = __builtin_amdgcn_readfirstlane(no_b[a0]);
            int eend = __builtin_amdgcn_readfirstlane(no_b[a1]);
            wave_stream(hbb, csr_b, ebeg, eend, a0, a1, lane, row0, aLo, aHi);
        }
    }
    __syncthreads();

    // ---- finalize: + branch B + biases, store f32 ----
    if (node >= n) return;
    float fb = dinv[n + node];
    const uint4* xbp = (const uint4*)(hbb + (size_t)node * 64 + cb * 8);
    uint4 c0 = xbp[0], c1 = xbp[1];
    uint ub[8];
    ub[0] = c0.x; ub[1] = c0.y; ub[2] = c0.z; ub[3] = c0.w;
    ub[4] = c1.x; ub[5] = c1.y; ub[6] = c1.z; ub[7] = c1.w;
    const float* aLB = aLo + r * 64 + cb * 8;
    const float* aHB = aHi + r * 64 + cb * 8;
#pragma unroll
    for (int k = 0; k < 8; ++k) {
        res[2 * k] += fb * (aLB[k] + bf2f((ushort)ub[k]));
        res[2 * k + 1] += fb * (aHB[k] + bf2f((ushort)(ub[k] >> 16)));
    }
    const float4* b2v = (const float4*)(b2 + cb * 16);
    const float4* b3v = (const float4*)(b3 + cb * 16);
    float4* op = (float4*)(out + (size_t)node * 128 + cb * 16);
#pragma unroll
    for (int i = 0; i < 4; ++i) {
        float4 bsum2 = b2v[i];
        float4 bsum3 = b3v[i];
        float4 o;
        o.x = res[4 * i + 0] + bsum2.x + bsum3.x;
        o.y = res[4 * i + 1] + bsum2.y + bsum3.y;
        o.z = res[4 * i + 2] + bsum2.z + bsum3.z;
        o.w = res[4 * i + 3] + bsum2.w + bsum3.w;
        op[i] = o;
    }
}

extern "C" void kernel_launch(void* const* d_in, const int* in_sizes, int n_in,
                              void* d_out, int out_size, void* d_ws, size_t ws_size,
                              hipStream_t stream) {
    const float* x    = (const float*)d_in[0];
    const int*   ei_a = (const int*)d_in[1];
    const int*   ei_b = (const int*)d_in[2];
    const float* W0 = (const float*)d_in[3];
    const float* b0 = (const float*)d_in[4];
    const float* W1 = (const float*)d_in[5];
    const float* b1 = (const float*)d_in[6];
    const float* W2 = (const float*)d_in[7];
    const float* b2 = (const float*)d_in[8];
    const float* W3 = (const float*)d_in[9];
    const float* b3 = (const float*)d_in[10];
    float* out = (float*)d_out;

    const int n = in_sizes[0] / 128;  // 50000 (< 2^17)
    const int e = in_sizes[1] / 2;    // 800000
    const int NB = (n + BKT - 1) / BKT;      // 196 (<= 256)
    const int NW = (e + CHUNK - 1) / CHUNK;  // 196 (<= 256)

    // workspace (~92 MB)
    float*  ws   = (float*)d_ws;
    float*  dinv = ws;                                // 2n
    uint*   xba  = (uint*)(ws + 2 * (size_t)n);       // 64n
    uint*   xbb  = xba + 64 * (size_t)n;              // 64n
    uint*   oa   = xbb + 64 * (size_t)n;              // 64n (bf16 g, branch a)
    uint*   ob   = oa + 64 * (size_t)n;               // 64n
    ushort* Wpb  = (ushort*)(ob + 64 * (size_t)n);    // 4*32768 ushort
    int* cnt_mat = (int*)(Wpb + 4 * 32768);           // 2*NW*NB
    int* wgoff   = cnt_mat + 2 * (size_t)NW * NB;     // 2*NB*NW
    int* btot    = wgoff + 2 * (size_t)NB * NW;       // 2*NB
    int* boff    = btot + 2 * NB;                     // 2*(NB+1)
    int* noff    = boff + 2 * (NB + 1);               // 2*(n+1)
    int* ebuf_a  = noff + 2 * (n + 1);                // e
    int* ebuf_b  = ebuf_a + e;                        // e
    int* csr_a   = ebuf_b + e;                        // e
    int* csr_b   = csr_a + e;                         // e

    const int B = 256;

    // --- CSR build (atomic-free) ---
    k_p1_hist<<<2 * NW, B, 0, stream>>>(ei_a, ei_b, cnt_mat, e, NB, NW);
    k_p2a<<<2 * NB, B, 0, stream>>>(cnt_mat, wgoff, btot, NB, NW);
    k_p2b<<<1, B, 0, stream>>>(btot, boff, NB, e);
    k_p3_scatter<<<2 * NW, B, 0, stream>>>(ei_a, ei_b, wgoff, boff, ebuf_a, ebuf_b, e, NB, NW);
    k_p4_nodesort<<<2 * NB, B, 0, stream>>>(ebuf_a, ebuf_b, boff, csr_a, csr_b, noff, dinv,
                                            n, e, NB);

    // --- conversions (fused cvt + weight pack) ---
    const int cvtb = (n * 64 + B - 1) / B;
    const int packb = (4 * 32768 + B - 1) / B;
    k_cvt_pack<<<cvtb + packb, B, 0, stream>>>((const float2*)x, dinv, xba, xbb,
                                               W0, W1, W2, W3, Wpb, n, cvtb);

    // --- fused layer-1 gather + MLP, both branches, XCD-branch partitioned ---
    const int nblk = (n + 31) / 32;
    const int grp4 = (nblk + 3) / 4;   // groups of 4 blocks; 2 branches alternate
    k_gather_mlp<<<grp4 * 8, B, 0, stream>>>(xba, xbb, csr_a, csr_b, noff, dinv, Wpb,
                                             b0, b1, (ushort*)oa, (ushort*)ob, n, nblk);

    // --- layer-2 aggregation + ensemble sum + bias (time-shared 16KB acc) ---
    k_gather_l2<<<nblk, B, 0, stream>>>(oa, ob, csr_a, csr_b, noff, dinv, b2, b3, out, n);
}